// Round 8
// baseline (127.060 us; speedup 1.0000x reference)
//
#include <hip/hip_runtime.h>

// CAN: per-sample 2-layer MLP, B=16384, N=50, D=16.
// R8: LDS-pipe elimination via transposed MFMA.
//   Key identity: 16x16x32 A-frag and B-frag have the same lane->(idx,k)
//   mapping, so C' = W^T @ x^T uses the SAME fragments argument-swapped.
//   - Layer-0 out C'[e][m] (col=m,row=e): lane holds 4 consecutive features
//     of row m -> inter-layer transpose = 4 ds_bpermute per tile (pack 2
//     dwords, broadcast). No __shared__, no __syncthreads anywhere.
//   - Layer-1 out D'[e][m]: lane stores 4 consecutive floats of row m ->
//     one global_store_dwordx4 per tile.
//   - W^T A-frags: 16 strided dword loads (quads 0-1); bias as per-quad
//     float4 (matches per-reg C-init layout); x^T B-frags: 8 float4 loads.
//     All ~26 loads issued up front; waves fully independent.

#define CAN_D 16
#define CAN_N 50
#define CAN_PSTRIDE 544
#define WAVES_PER_BLOCK 4

typedef __attribute__((ext_vector_type(8))) short short8;   // 8 bf16
typedef __attribute__((ext_vector_type(4))) float f32x4;

union ABFrag { int i[4]; short8 v; };

// RNE fp32->bf16, lo -> bits [15:0]
__device__ __forceinline__ int pack2(float lo, float hi) {
    unsigned short ua = __builtin_bit_cast(unsigned short, (__bf16)lo);
    unsigned short ub = __builtin_bit_cast(unsigned short, (__bf16)hi);
    return (int)((unsigned)ua | ((unsigned)ub << 16));
}

__global__ __launch_bounds__(256, 4) void can_kernel(
    const float* __restrict__ user_emb,
    const float* __restrict__ item_emb,
    float* __restrict__ out, int B)
{
    const int wave = threadIdx.x >> 6;
    const int lane = threadIdx.x & 63;
    const int s = blockIdx.x * WAVES_PER_BLOCK + wave;
    if (s >= B) return;                  // wave-uniform

    const int e    = lane & 15;          // element idx (A row / B col / C col)
    const int quad = lane >> 4;

    const float* __restrict__ P  = item_emb + (size_t)s * CAN_PSTRIDE;
    const float* __restrict__ xb = user_emb + (size_t)s * (CAN_N * CAN_D);
    float* __restrict__ ob       = out      + (size_t)s * (CAN_N * CAN_D);

    // ---- A-frags = W^T: lane (e, quad<2) holds W[k=quad*8+j][e]
    //      (same elements as the old B-frag; as A it reads W^T[e][k])
    ABFrag w0, w1;
    if (quad < 2) {
        float t0[8], t1[8];
#pragma unroll
        for (int j = 0; j < 8; ++j) {
            t0[j] = P[(quad * 8 + j) * CAN_D + e];
            t1[j] = P[272 + (quad * 8 + j) * CAN_D + e];
        }
#pragma unroll
        for (int j = 0; j < 4; ++j) {
            w0.i[j] = pack2(t0[2 * j], t0[2 * j + 1]);
            w1.i[j] = pack2(t1[2 * j], t1[2 * j + 1]);
        }
    } else {
#pragma unroll
        for (int j = 0; j < 4; ++j) { w0.i[j] = 0; w1.i[j] = 0; }
    }

    // ---- biases: C'-init needs reg r = b[quad*4 + r] -> per-quad float4
    const float4 b0q = *(const float4*)(P + 256 + 4 * quad);
    const float4 b1q = *(const float4*)(P + 528 + 4 * quad);

    // ---- B-frags = x^T for all 4 tiles: lane (m=e, quad<2) holds
    //      x[t*16+m][k=quad*8+j] (same construction as the old A-frag)
    ABFrag xf[4];
#pragma unroll
    for (int t = 0; t < 4; ++t) {
        if (quad < 2) {
            int row = t * 16 + e;
            if (row > CAN_N - 1) row = CAN_N - 1;   // clamp; masked at store
            const float4* pr = (const float4*)(xb + row * CAN_D + quad * 8);
            float4 u0 = pr[0], u1 = pr[1];
            xf[t].i[0] = pack2(u0.x, u0.y);
            xf[t].i[1] = pack2(u0.z, u0.w);
            xf[t].i[2] = pack2(u1.x, u1.y);
            xf[t].i[3] = pack2(u1.z, u1.w);
        } else {
#pragma unroll
            for (int j = 0; j < 4; ++j) xf[t].i[j] = 0;
        }
    }

    // bpermute byte-addresses for the layer transition:
    // dest lane (m, q) takes y[m][8q..8q+3] from lane m+32(q&1), and
    // y[m][8q+4..8q+7] from lane m+32(q&1)+16.  (quads 2,3 zeroed: k>=16)
    const int addrA = ((lane & 15) + (quad & 1) * 32) * 4;
    const int addrB = addrA + 64;

#pragma unroll
    for (int t = 0; t < 4; ++t) {
        // ---- layer 0 (transposed): C'[e][m] = sum_k W0[k][e] x[m][k] + b0[e]
        f32x4 c = {b0q.x, b0q.y, b0q.z, b0q.w};
        c = __builtin_amdgcn_mfma_f32_16x16x32_bf16(w0.v, xf[t].v, c, 0, 0, 0);

        // relu + pack this lane's 4 consecutive features of row m
        const int p0 = pack2(fmaxf(c[0], 0.f), fmaxf(c[1], 0.f));
        const int p1 = pack2(fmaxf(c[2], 0.f), fmaxf(c[3], 0.f));

        // ---- transpose via 4 bpermutes -> layer-1 B-frag (y^T)
        ABFrag a1;
        a1.i[0] = __builtin_amdgcn_ds_bpermute(addrA, p0);
        a1.i[1] = __builtin_amdgcn_ds_bpermute(addrA, p1);
        a1.i[2] = __builtin_amdgcn_ds_bpermute(addrB, p0);
        a1.i[3] = __builtin_amdgcn_ds_bpermute(addrB, p1);
        if (quad >= 2) {
#pragma unroll
            for (int j = 0; j < 4; ++j) a1.i[j] = 0;
        }

        // ---- layer 1 (transposed): D'[e][m]
        f32x4 d = {b1q.x, b1q.y, b1q.z, b1q.w};
        d = __builtin_amdgcn_mfma_f32_16x16x32_bf16(w1.v, a1.v, d, 0, 0, 0);

        // ---- relu + ONE float4 store: out[t*16+m][quad*4 .. +3]
        const int grow = t * 16 + e;
        if (grow < CAN_N) {
            float4 ov = make_float4(fmaxf(d[0], 0.f), fmaxf(d[1], 0.f),
                                    fmaxf(d[2], 0.f), fmaxf(d[3], 0.f));
            *(float4*)(ob + grow * CAN_D + quad * 4) = ov;
        }
    }
}

extern "C" void kernel_launch(void* const* d_in, const int* in_sizes, int n_in,
                              void* d_out, int out_size, void* d_ws, size_t ws_size,
                              hipStream_t stream) {
    const float* user_emb = (const float*)d_in[0];
    const float* item_emb = (const float*)d_in[1];
    float* out = (float*)d_out;

    const int B = in_sizes[0] / (CAN_N * CAN_D);   // 16384
    const int blocks = (B + WAVES_PER_BLOCK - 1) / WAVES_PER_BLOCK;
    can_kernel<<<blocks, 256, 0, stream>>>(user_emb, item_emb, out, B);
}